// Round 16
// baseline (574.656 us; speedup 1.0000x reference)
//
#include <hip/hip_runtime.h>
#include <hip/hip_bf16.h>
#include <type_traits>

// ---------------------------------------------------------------------------
// ROLAND GNN forward. Buffers f32; matmuls bf16-MFMA, f32 accum.
// Outputs (concat, f32): logits[EL], emb0[N,128], emb1[N,128], emb2[N,128]
// Round 16: degree-sorted row perm, generated WITHOUT concentrated atomics
// (LDS int histogram -> single-block scan -> scatter). gg consumes perm
// (validated r13) so each 64-row block has near-uniform degree -> block
// gather time ~ mean deg instead of max-of-64.
// ---------------------------------------------------------------------------

typedef __bf16 bf16;
typedef __bf16 bf16x8 __attribute__((ext_vector_type(8)));
typedef float  f32x4  __attribute__((ext_vector_type(4)));

#define DEV __device__ __forceinline__

DEV f32x4 mfma16(bf16x8 a, bf16x8 b, f32x4 c) {
    return __builtin_amdgcn_mfma_f32_16x16x32_bf16(a, b, c, 0, 0, 0);
}

DEV bf16x8 load_a8(const float* p) {
    f32x4 lo = *(const f32x4*)p;
    f32x4 hi = *(const f32x4*)(p + 4);
    bf16x8 v;
    v[0] = (bf16)lo[0]; v[1] = (bf16)lo[1]; v[2] = (bf16)lo[2]; v[3] = (bf16)lo[3];
    v[4] = (bf16)hi[0]; v[5] = (bf16)hi[1]; v[6] = (bf16)hi[2]; v[7] = (bf16)hi[3];
    return v;
}
DEV bf16x8 load_a8(const bf16* p) { return *(const bf16x8*)p; }

// single fused f32->bf16 conversion of all 8 weight matrices into wb
__global__ void cvt8_kernel(const float* s0, const float* s1, const float* s2, const float* s3,
                            const float* s4, const float* s5, const float* s6, const float* s7,
                            bf16* __restrict__ wb) {
    const int i = blockIdx.x * 256 + threadIdx.x;
    if (i >= 294912) return;
    float v;
    if      (i < 32768)  v = s0[i];
    else if (i < 65536)  v = s1[i - 32768];
    else if (i < 81920)  v = s2[i - 65536];
    else if (i < 98304)  v = s3[i - 81920];
    else if (i < 147456) v = s4[i - 98304];
    else if (i < 196608) v = s5[i - 147456];
    else if (i < 245760) v = s6[i - 196608];
    else                 v = s7[i - 245760];
    wb[i] = (bf16)v;
}

// ---------------------------------------------------------------------------
// GEMM: C[M,Co] = act(A[M,Ci] @ W[Co,Ci]^T + bias). 2 M-tiles/wave.
// MFMA 16x16x32 bf16; C/D layout (m89): col=lane&15, row=4*(lane>>4)+j.
// ---------------------------------------------------------------------------
template<int Ci, int Co, bool ACT, bool BIAS, typename AT, typename OT>
__global__ __launch_bounds__(256) void gemm_kernel(
    const AT* __restrict__ A, const bf16* __restrict__ W,
    const float* __restrict__ bias, OT* __restrict__ C, int M)
{
    const int tid  = threadIdx.x;
    const int lane = tid & 63, w = tid >> 6;
    const int lr   = lane & 15, ko = lane >> 4;
    const int rbase = blockIdx.x * 128 + w * 32;

    constexpr int KC = Ci / 32;
    constexpr int NT = Co / 16;

    bf16x8 a[2][KC];
#pragma unroll
    for (int m = 0; m < 2; ++m) {
        long arow = rbase + m * 16 + lr; if (arow > M - 1) arow = M - 1;  // clamped rows never stored
#pragma unroll
        for (int kc = 0; kc < KC; ++kc)
            a[m][kc] = load_a8(A + arow * Ci + kc * 32 + ko * 8);
    }

#pragma unroll
    for (int t = 0; t < NT; ++t) {
        f32x4 acc0 = {0.f, 0.f, 0.f, 0.f};
        f32x4 acc1 = {0.f, 0.f, 0.f, 0.f};
        const bf16* wp = W + (long)(t * 16 + lr) * Ci + ko * 8;
#pragma unroll
        for (int kc = 0; kc < KC; ++kc) {
            bf16x8 wf = *(const bf16x8*)(wp + kc * 32);
            acc0 = mfma16(a[0][kc], wf, acc0);
            acc1 = mfma16(a[1][kc], wf, acc1);
        }

        const int col = t * 16 + lr;
        float bv = 0.f;
        if (BIAS) bv = bias[col];
#pragma unroll
        for (int j = 0; j < 4; ++j) {
            const int r0 = rbase + ko * 4 + j;
            if (r0 < M) {
                float v = acc0[j] + bv;
                if (ACT) v = (v >= 0.f) ? v : 0.01f * v;
                C[(long)r0 * Co + col] = (OT)v;
            }
            const int r1 = rbase + 16 + ko * 4 + j;
            if (r1 < M) {
                float v = acc1[j] + bv;
                if (ACT) v = (v >= 0.f) ? v : 0.01f * v;
                C[(long)r1 * Co + col] = (OT)v;
            }
        }
    }
}

// ---------------------------------------------------------------------------
// GRUCell, 64-row blocks (4 waves x 16 rows), LDS weight tiles + reg prefetch.
// Safe for out == x (f32 path): all A-frag reads precede the first barrier.
// ---------------------------------------------------------------------------
template<typename XT>
__global__ __launch_bounds__(256) void gru_kernel(
    const XT* x, const float* __restrict__ hp,
    const bf16* __restrict__ wih, const bf16* __restrict__ whh,
    const float* __restrict__ bih, const float* __restrict__ bhh,
    float* out, int N)
{
    __shared__ bf16 Lw[6][16][128];   // 24 KB

    const int tid  = threadIdx.x;
    const int lane = tid & 63, w = tid >> 6;
    const int lr   = lane & 15, ko = lane >> 4;
    const long rbase = (long)blockIdx.x * 64 + w * 16;

    long arow = rbase + lr; if (arow > N - 1) arow = N - 1;
    bf16x8 ax[4], ah[4];
#pragma unroll
    for (int kc = 0; kc < 4; ++kc) {
        ax[kc] = load_a8(x  + arow * 128 + kc * 32 + ko * 8);
        ah[kc] = load_a8(hp + arow * 128 + kc * 32 + ko * 8);
    }

    bf16x8 pre[6];
    auto LDW = [&](int tc) {
#pragma unroll
        for (int i = 0; i < 6; ++i) {
            const int ch  = tid + 256 * i;
            const int g   = ch >> 8, rem = ch & 255;
            const int row = rem >> 4, cc = rem & 15;
            const int scc = cc ^ (row & 7);
            pre[i] = *(const bf16x8*)((g < 3 ? wih : whh)
                + (long)(((g % 3) * 128 + tc * 16 + row) * 128 + scc * 8));
        }
    };
    LDW(0);

    for (int tc = 0; tc < 8; ++tc) {
        __syncthreads();
#pragma unroll
        for (int i = 0; i < 6; ++i) {
            const int ch  = tid + 256 * i;
            const int g   = ch >> 8, rem = ch & 255;
            const int row = rem >> 4, cc = rem & 15;
            *(bf16x8*)(&Lw[g][row][cc * 8]) = pre[i];
        }
        __syncthreads();
        if (tc < 7) LDW(tc + 1);

        const int col = tc * 16 + lr;
        const float br = bih[col]       + bhh[col];
        const float bz = bih[128 + col] + bhh[128 + col];
        const float bi = bih[256 + col];
        const float bh = bhh[256 + col];

        f32x4 ar = {0.f, 0.f, 0.f, 0.f};
        f32x4 az = {0.f, 0.f, 0.f, 0.f};
        f32x4 ai = {0.f, 0.f, 0.f, 0.f};
        f32x4 ag = {0.f, 0.f, 0.f, 0.f};
#pragma unroll
        for (int kc = 0; kc < 4; ++kc) {
            const int cc = (kc * 4 + ko) ^ (lr & 7);
            bf16x8 wr_i = *(const bf16x8*)(&Lw[0][lr][cc * 8]);
            bf16x8 wz_i = *(const bf16x8*)(&Lw[1][lr][cc * 8]);
            bf16x8 wn_i = *(const bf16x8*)(&Lw[2][lr][cc * 8]);
            bf16x8 wr_h = *(const bf16x8*)(&Lw[3][lr][cc * 8]);
            bf16x8 wz_h = *(const bf16x8*)(&Lw[4][lr][cc * 8]);
            bf16x8 wn_h = *(const bf16x8*)(&Lw[5][lr][cc * 8]);
            ar = mfma16(ax[kc], wr_i, ar);
            ar = mfma16(ah[kc], wr_h, ar);
            az = mfma16(ax[kc], wz_i, az);
            az = mfma16(ah[kc], wz_h, az);
            ai = mfma16(ax[kc], wn_i, ai);
            ag = mfma16(ah[kc], wn_h, ag);
        }
#pragma unroll
        for (int j = 0; j < 4; ++j) {
            const long row = rbase + ko * 4 + j;
            if (row < N) {
                const float r = 1.f / (1.f + __expf(-(ar[j] + br)));
                const float z = 1.f / (1.f + __expf(-(az[j] + bz)));
                const float pre_ = (ai[j] + bi) + r * (ag[j] + bh);
                const float n = 1.f - 2.f / (1.f + __expf(2.f * pre_));
                out[row * 128 + col] = (1.f - z) * n + z * hp[row * 128 + col];
            }
        }
    }
}

// ---------------------------------------------------------------------------
// FUSED gather + GRU with degree-sorted perm (r13-validated consumption) and
// packed/2-edge-unrolled gather (r15). Block's 64 rows = perm[rbase..rbase+64)
// have near-equal degree -> block gather time ~ mean deg, not max-of-64.
// ---------------------------------------------------------------------------
__global__ __launch_bounds__(256) void gg_kernel(
    const bf16* __restrict__ xwb,
    const int* __restrict__ rowptr, const int* __restrict__ degi,
    const int2* __restrict__ csr_pk, const int* __restrict__ perm,
    const float* __restrict__ dinv, const float* __restrict__ cbias,
    const float* __restrict__ hp,
    const bf16* __restrict__ wih, const bf16* __restrict__ whh,
    const float* __restrict__ bih, const float* __restrict__ bhh,
    float* __restrict__ out, int N)
{
    __shared__ bf16 Lw[6][16][128];   // 24 KB
    __shared__ int  sperm[64];

    const int tid  = threadIdx.x;
    const int lane = tid & 63, w = tid >> 6;
    const int lr   = lane & 15, ko = lane >> 4;
    const long rbase = (long)blockIdx.x * 64;
    const long wrow0 = rbase + w * 16;

    if (tid < 64) {
        long ii = rbase + tid; if (ii > N - 1) ii = N - 1;
        sperm[tid] = perm[ii];     // tail duplicates benign (identical values, guarded)
    }
    __syncthreads();

    const long arow = sperm[w * 16 + lr];

    // ---- gather phase: 2-edge unrolled, packed records ----
    float acc[4][8];
#pragma unroll
    for (int kc = 0; kc < 4; ++kc)
#pragma unroll
        for (int j = 0; j < 8; ++j) acc[kc][j] = 0.f;
    {
        const int start = rowptr[arow];
        const int deg   = degi[arow];
        const bf16* xb  = xwb + ko * 8;
        int k = 0;
        for (; k + 2 <= deg; k += 2) {
            const int2 p0 = csr_pk[start + k];
            const int2 p1 = csr_pk[start + k + 1];
            const float nm0 = __int_as_float(p0.y);
            const float nm1 = __int_as_float(p1.y);
            const bf16* vp0 = xb + (long)p0.x * 128;
            const bf16* vp1 = xb + (long)p1.x * 128;
            bf16x8 a0 = *(const bf16x8*)(vp0);
            bf16x8 a1 = *(const bf16x8*)(vp0 + 32);
            bf16x8 a2 = *(const bf16x8*)(vp0 + 64);
            bf16x8 a3 = *(const bf16x8*)(vp0 + 96);
            bf16x8 b0 = *(const bf16x8*)(vp1);
            bf16x8 b1 = *(const bf16x8*)(vp1 + 32);
            bf16x8 b2 = *(const bf16x8*)(vp1 + 64);
            bf16x8 b3 = *(const bf16x8*)(vp1 + 96);
#pragma unroll
            for (int j = 0; j < 8; ++j) {
                acc[0][j] += (float)a0[j] * nm0 + (float)b0[j] * nm1;
                acc[1][j] += (float)a1[j] * nm0 + (float)b1[j] * nm1;
                acc[2][j] += (float)a2[j] * nm0 + (float)b2[j] * nm1;
                acc[3][j] += (float)a3[j] * nm0 + (float)b3[j] * nm1;
            }
        }
        if (k < deg) {
            const int2 p0 = csr_pk[start + k];
            const float nm0 = __int_as_float(p0.y);
            const bf16* vp0 = xb + (long)p0.x * 128;
            bf16x8 a0 = *(const bf16x8*)(vp0);
            bf16x8 a1 = *(const bf16x8*)(vp0 + 32);
            bf16x8 a2 = *(const bf16x8*)(vp0 + 64);
            bf16x8 a3 = *(const bf16x8*)(vp0 + 96);
#pragma unroll
            for (int j = 0; j < 8; ++j) {
                acc[0][j] += (float)a0[j] * nm0;
                acc[1][j] += (float)a1[j] * nm0;
                acc[2][j] += (float)a2[j] * nm0;
                acc[3][j] += (float)a3[j] * nm0;
            }
        }
    }

    bf16x8 ax[4], ah[4];
    {
        const float di = dinv[arow], sl = di * di;
        const bf16* vp = xwb + (long)arow * 128 + ko * 8;
#pragma unroll
        for (int kc = 0; kc < 4; ++kc) {
            bf16x8 vd = *(const bf16x8*)(vp + kc * 32);
#pragma unroll
            for (int j = 0; j < 8; ++j) {
                float t = acc[kc][j] + (float)vd[j] * sl + cbias[kc * 32 + ko * 8 + j];
                t = (t >= 0.f) ? t : 0.01f * t;
                ax[kc][j] = (bf16)t;
            }
            ah[kc] = load_a8(hp + arow * 128 + kc * 32 + ko * 8);
        }
    }

    // ---- GRU phase ----
    bf16x8 pre[6];
    auto LDW = [&](int tc) {
#pragma unroll
        for (int i = 0; i < 6; ++i) {
            const int ch  = tid + 256 * i;
            const int g   = ch >> 8, rem = ch & 255;
            const int row = rem >> 4, cc = rem & 15;
            const int scc = cc ^ (row & 7);
            pre[i] = *(const bf16x8*)((g < 3 ? wih : whh)
                + (long)(((g % 3) * 128 + tc * 16 + row) * 128 + scc * 8));
        }
    };
    LDW(0);

    for (int tc = 0; tc < 8; ++tc) {
        __syncthreads();
#pragma unroll
        for (int i = 0; i < 6; ++i) {
            const int ch  = tid + 256 * i;
            const int g   = ch >> 8, rem = ch & 255;
            const int row = rem >> 4, cc = rem & 15;
            *(bf16x8*)(&Lw[g][row][cc * 8]) = pre[i];
        }
        __syncthreads();
        if (tc < 7) LDW(tc + 1);

        const int col = tc * 16 + lr;
        const float br = bih[col]       + bhh[col];
        const float bz = bih[128 + col] + bhh[128 + col];
        const float bi = bih[256 + col];
        const float bh = bhh[256 + col];

        f32x4 ar = {0.f, 0.f, 0.f, 0.f};
        f32x4 az = {0.f, 0.f, 0.f, 0.f};
        f32x4 ai = {0.f, 0.f, 0.f, 0.f};
        f32x4 ag = {0.f, 0.f, 0.f, 0.f};
        __builtin_amdgcn_s_setprio(1);
#pragma unroll
        for (int kc = 0; kc < 4; ++kc) {
            const int cc = (kc * 4 + ko) ^ (lr & 7);
            bf16x8 wr_i = *(const bf16x8*)(&Lw[0][lr][cc * 8]);
            bf16x8 wz_i = *(const bf16x8*)(&Lw[1][lr][cc * 8]);
            bf16x8 wn_i = *(const bf16x8*)(&Lw[2][lr][cc * 8]);
            bf16x8 wr_h = *(const bf16x8*)(&Lw[3][lr][cc * 8]);
            bf16x8 wz_h = *(const bf16x8*)(&Lw[4][lr][cc * 8]);
            bf16x8 wn_h = *(const bf16x8*)(&Lw[5][lr][cc * 8]);
            ar = mfma16(ax[kc], wr_i, ar);
            ar = mfma16(ah[kc], wr_h, ar);
            az = mfma16(ax[kc], wz_i, az);
            az = mfma16(ah[kc], wz_h, az);
            ai = mfma16(ax[kc], wn_i, ai);
            ag = mfma16(ah[kc], wn_h, ag);
        }
        __builtin_amdgcn_s_setprio(0);
#pragma unroll
        for (int j = 0; j < 4; ++j) {
            if (wrow0 + ko * 4 + j < N) {          // only real slots write
                const long row = sperm[w * 16 + ko * 4 + j];
                const float r = 1.f / (1.f + __expf(-(ar[j] + br)));
                const float z = 1.f / (1.f + __expf(-(az[j] + bz)));
                const float pre_ = (ai[j] + bi) + r * (ag[j] + bh);
                const float n = 1.f - 2.f / (1.f + __expf(2.f * pre_));
                out[row * 128 + col] = (1.f - z) * n + z * hp[row * 128 + col];
            }
        }
    }
}

// ---------------------------------------------------------------------------
// CSR build chain (kernel-boundary sync; NO grid.sync; NO concentrated atomics)
// ---------------------------------------------------------------------------
__global__ void deg_kernel(const int* __restrict__ dst, int* degi, int E) {
    const int e = blockIdx.x * 256 + threadIdx.x;
    if (e < E) atomicAdd(&degi[dst[e]], 1);
}
__global__ void scan1_kernel(const int* __restrict__ degi, int* __restrict__ inc,
                             int* __restrict__ bsum, float* __restrict__ dinv, int N) {
    __shared__ int s[256];
    const int i = blockIdx.x * 256 + threadIdx.x;
    const int d = (i < N) ? degi[i] : 0;
    if (i < N) dinv[i] = rsqrtf((float)d + 1.0f);   // +1 self loop
    s[threadIdx.x] = d;
    __syncthreads();
#pragma unroll
    for (int off = 1; off < 256; off <<= 1) {
        int t = (threadIdx.x >= off) ? s[threadIdx.x - off] : 0;
        __syncthreads();
        s[threadIdx.x] += t;
        __syncthreads();
    }
    if (i < N) inc[i] = s[threadIdx.x];
    if (threadIdx.x == 255) bsum[blockIdx.x] = s[255];
}
__global__ void scan2_kernel(int* bsum, int nb) {
    __shared__ int s[512];
    __shared__ int carry;
    if (threadIdx.x == 0) carry = 0;
    __syncthreads();
    for (int base = 0; base < nb; base += 512) {
        const int i = base + threadIdx.x;
        s[threadIdx.x] = (i < nb) ? bsum[i] : 0;
        __syncthreads();
#pragma unroll
        for (int off = 1; off < 512; off <<= 1) {
            int t = (threadIdx.x >= off) ? s[threadIdx.x - off] : 0;
            __syncthreads();
            s[threadIdx.x] += t;
            __syncthreads();
        }
        const int c = carry;
        if (i < nb) bsum[i] = s[threadIdx.x] + c;
        __syncthreads();
        if (threadIdx.x == 511) carry = c + s[511];
        __syncthreads();
    }
}
__global__ void scan3_kernel(const int* __restrict__ inc, const int* __restrict__ degi,
                             const int* __restrict__ bsum, int* __restrict__ rowptr,
                             int* __restrict__ rp2, int N) {
    const int i = blockIdx.x * 256 + threadIdx.x;
    if (i >= N) return;
    const int prev = (blockIdx.x > 0) ? bsum[blockIdx.x - 1] : 0;
    const int rp = prev + inc[i] - degi[i];   // exclusive prefix
    rowptr[i] = rp;
    rp2[i]    = rp;
}
__global__ void fill_kernel(const int* __restrict__ src, const int* __restrict__ dst,
                            int* rp2, const float* __restrict__ dinv,
                            int2* __restrict__ csr_pk, int E) {
    const int e = blockIdx.x * 256 + threadIdx.x;
    if (e >= E) return;
    const int s = src[e], d = dst[e];
    const int pos = atomicAdd(&rp2[d], 1);
    csr_pk[pos] = make_int2(s, __float_as_int(dinv[s] * dinv[d]));
}

// ---- degree-sort perm, hierarchical (no concentrated atomics) ----
// bhist: per-256-node block 64-bin LDS int histogram; record (bin, rank).
__global__ void bhist_kernel(const int* __restrict__ degi, int* __restrict__ binof,
                             int* __restrict__ rankin, int* __restrict__ bh,
                             int N, int nbB) {
    __shared__ int h[64];
    const int i = blockIdx.x * 256 + threadIdx.x;
    if (threadIdx.x < 64) h[threadIdx.x] = 0;
    __syncthreads();
    if (i < N) {
        int b = degi[i]; if (b > 63) b = 63;
        const int r = atomicAdd(&h[b], 1);     // LDS int atomic (native ds_add_rtn)
        binof[i]  = b;
        rankin[i] = r;
    }
    __syncthreads();
    if (threadIdx.x < 64) bh[threadIdx.x * nbB + blockIdx.x] = h[threadIdx.x];
}
// gscan: exclusive scan of bh[total] in place; 1 block, serial segments.
__global__ void gscan_kernel(int* bh, int total) {
    __shared__ int ssum[256];
    const int t = threadIdx.x;
    const int seg = (total + 255) / 256;
    const int s0 = t * seg;
    const int s1 = (s0 + seg < total) ? (s0 + seg) : total;
    int sum = 0;
    for (int i = s0; i < s1; ++i) sum += bh[i];
    ssum[t] = sum;
    __syncthreads();
#pragma unroll
    for (int off = 1; off < 256; off <<= 1) {
        int v = (t >= off) ? ssum[t - off] : 0;
        __syncthreads();
        ssum[t] += v;
        __syncthreads();
    }
    int run = ssum[t] - sum;   // exclusive base of this segment
    for (int i = s0; i < s1; ++i) {
        const int v = bh[i];
        bh[i] = run;
        run += v;
    }
}
// pscatter: perm[offset(bin,block) + rank] = node. Unique positions, no atomics.
__global__ void pscatter_kernel(const int* __restrict__ binof, const int* __restrict__ rankin,
                                const int* __restrict__ bh, int* __restrict__ perm,
                                int N, int nbB) {
    const int i = blockIdx.x * 256 + threadIdx.x;
    if (i >= N) return;
    const int pos = bh[binof[i] * nbB + blockIdx.x] + rankin[i];
    perm[pos] = i;
}

// ---------------------------------------------------------------------------
// Standalone gather (fallback path for small ws / column passes)
// ---------------------------------------------------------------------------
template<typename OT>
__global__ __launch_bounds__(256) void gather_kernel(
    const bf16* __restrict__ xwb,
    const int* __restrict__ rowptr, const int* __restrict__ degi,
    const int2* __restrict__ csr_pk,
    const float* __restrict__ dinv, const float* __restrict__ bias,
    OT* __restrict__ out, int N, int colbase, int cw, int lg)
{
    const long tid = (long)blockIdx.x * 256 + threadIdx.x;
    const long d = tid >> lg;
    const int  c = (int)(tid & ((1 << lg) - 1));
    if (d >= N) return;

    const int start = rowptr[d];
    const int deg   = degi[d];
    const int h     = deg >> 1;
    const bf16* xb  = xwb + c * 8;

    float acca[8] = {0.f, 0.f, 0.f, 0.f, 0.f, 0.f, 0.f, 0.f};
    float accb[8] = {0.f, 0.f, 0.f, 0.f, 0.f, 0.f, 0.f, 0.f};
    for (int k = 0; k < h; ++k) {
        const int2 pa = csr_pk[start + k];
        const int2 pb = csr_pk[start + h + k];
        bf16x8 va = *(const bf16x8*)(xb + (long)pa.x * cw);
        bf16x8 vb = *(const bf16x8*)(xb + (long)pb.x * cw);
        const float na  = __int_as_float(pa.y);
        const float nb_ = __int_as_float(pb.y);
#pragma unroll
        for (int j = 0; j < 8; ++j) {
            acca[j] += (float)va[j] * na;
            accb[j] += (float)vb[j] * nb_;
        }
    }
    if (deg & 1) {
        const int2 pa = csr_pk[start + deg - 1];
        const float nm = __int_as_float(pa.y);
        bf16x8 v = *(const bf16x8*)(xb + (long)pa.x * cw);
#pragma unroll
        for (int j = 0; j < 8; ++j) acca[j] += (float)v[j] * nm;
    }

    const float di = dinv[d], sl = di * di;
    bf16x8 vd = *(const bf16x8*)(xb + d * cw);
    const int col = colbase + c * 8;
    float v[8];
#pragma unroll
    for (int j = 0; j < 8; ++j) {
        float t = acca[j] + accb[j] + (float)vd[j] * sl + bias[col + j];
        v[j] = (t >= 0.f) ? t : 0.01f * t;
    }
    if constexpr (std::is_same<OT, bf16>::value) {
        bf16x8 o;
#pragma unroll
        for (int j = 0; j < 8; ++j) o[j] = (bf16)v[j];
        *(bf16x8*)(out + d * 128 + col) = o;
    } else {
        f32x4 o0, o1;
#pragma unroll
        for (int j = 0; j < 4; ++j) { o0[j] = v[j]; o1[j] = v[4 + j]; }
        *(f32x4*)(out + d * 128 + col)     = o0;
        *(f32x4*)(out + d * 128 + col + 4) = o1;
    }
}

// ---------------------------------------------------------------------------
// LP head: 16 lanes per edge, shfl reduce.
// ---------------------------------------------------------------------------
__global__ __launch_bounds__(256) void lp_kernel(
    const float* __restrict__ emb, const int* __restrict__ eli,
    const float* __restrict__ wpost, const float* __restrict__ bpost,
    float* __restrict__ logits, int EL)
{
    const long t = (long)blockIdx.x * 256 + threadIdx.x;
    const long e = t >> 4;
    const int  c = (int)(t & 15);
    if (e >= EL) return;
    const long s = eli[e], d = eli[EL + e];

    f32x4 a0 = *(const f32x4*)(emb + s * 128 + c * 8);
    f32x4 a1 = *(const f32x4*)(emb + s * 128 + c * 8 + 4);
    f32x4 b0 = *(const f32x4*)(emb + d * 128 + c * 8);
    f32x4 b1 = *(const f32x4*)(emb + d * 128 + c * 8 + 4);
    f32x4 w00 = *(const f32x4*)(wpost + c * 8);
    f32x4 w01 = *(const f32x4*)(wpost + c * 8 + 4);
    f32x4 w10 = *(const f32x4*)(wpost + 128 + c * 8);
    f32x4 w11 = *(const f32x4*)(wpost + 128 + c * 8 + 4);

    float acc = 0.f;
#pragma unroll
    for (int i = 0; i < 4; ++i) {
        acc += a0[i] * b0[i] * (w00[i] + w10[i]);
        acc += a1[i] * b1[i] * (w01[i] + w11[i]);
    }
#pragma unroll
    for (int m = 1; m < 16; m <<= 1) acc += __shfl_xor(acc, m);
    if (c == 0) logits[e] = acc + bpost[0] + bpost[1];
}

// ---------------------------------------------------------------------------
extern "C" void kernel_launch(void* const* d_in, const int* in_sizes, int n_in,
                              void* d_out, int out_size, void* d_ws, size_t ws_size,
                              hipStream_t stream) {
    const float* x      = (const float*)d_in[0];
    const int*   ei     = (const int*)d_in[1];   // [2,E]: row0=src, row1=dst
    const int*   eli    = (const int*)d_in[2];
    const float* prev0  = (const float*)d_in[3];
    const float* prev1  = (const float*)d_in[4];
    const float* w_pre1 = (const float*)d_in[5];
    const float* b_pre1 = (const float*)d_in[6];
    const float* w_pre2 = (const float*)d_in[7];
    const float* b_pre2 = (const float*)d_in[8];
    const float* w_c1   = (const float*)d_in[9];
    const float* b_c1   = (const float*)d_in[10];
    const float* w_c2   = (const float*)d_in[11];
    const float* b_c2   = (const float*)d_in[12];
    const float* w_post = (const float*)d_in[13];
    const float* b_post = (const float*)d_in[14];
    const float* g1_wih = (const float*)d_in[15];
    const float* g1_whh = (const float*)d_in[16];
    const float* g1_bih = (const float*)d_in[17];
    const float* g1_bhh = (const float*)d_in[18];
    const float* g2_wih = (const float*)d_in[19];
    const float* g2_whh = (const float*)d_in[20];
    const float* g2_bih = (const float*)d_in[21];
    const float* g2_bhh = (const float*)d_in[22];

    const int N  = in_sizes[0] / 128;
    const int E  = in_sizes[1] / 2;
    const int EL = in_sizes[2] / 2;
    const long NH = (long)N * 128;

    // outputs (f32)
    float* out    = (float*)d_out;
    float* logits = out;
    float* emb0   = out + EL;
    float* emb1   = emb0 + NH;
    float* emb2   = emb1 + NH;

    // bf16 intermediates in currently-dead output slots
    bf16* H1b = (bf16*)emb1;   // [N,256] bf16 == emb1 slot
    bf16* H2b = (bf16*)emb2;   // [N,128] bf16 (first half of emb2 slot)
    bf16* h1b = (bf16*)emb2;   // fallback only

    // ---- workspace layout ----
    char* ws = (char*)d_ws;
    size_t p = 0;
    auto alloc = [&](size_t bytes) { size_t o = p; p = (p + bytes + 255) & ~(size_t)255; return o; };
    const int nbB = (N + 255) / 256;
    float* dinv    = (float*)(ws + alloc((size_t)N * 4));
    int*   degi    = (int*)  (ws + alloc((size_t)N * 4));
    int*   inc     = (int*)  (ws + alloc((size_t)N * 4));
    int*   rowptr  = (int*)  (ws + alloc((size_t)(N + 1) * 4));
    int*   rp2     = (int*)  (ws + alloc((size_t)N * 4));
    int*   bsum    = (int*)  (ws + alloc(4096));
    int*   binof   = (int*)  (ws + alloc((size_t)N * 4));
    int*   rankin  = (int*)  (ws + alloc((size_t)N * 4));
    int*   bh      = (int*)  (ws + alloc((size_t)64 * nbB * 4));
    int*   perm    = (int*)  (ws + alloc((size_t)N * 4));
    bf16*  wb      = (bf16*) (ws + alloc((size_t)294912 * 2));
    int2*  csr_pk  = (int2*) (ws + alloc((size_t)E * 8));
    const size_t fixed = p;
    bf16*  xwb     = (bf16*)(ws + fixed);

    int cw = 128;
    while (cw > 16 && fixed + (size_t)N * cw * 2 > ws_size) cw >>= 1;
    const int lg = __builtin_ctz(cw >> 3);
    const int passes = 128 / cw;
    const bool fused = (cw == 128);
    const bool big_ws = fused &&
        (ws_size >= fixed + (size_t)N * 128 * 2 + (size_t)N * 128 * 2);
    bf16* h2b = big_ws ? (bf16*)(ws + fixed + (size_t)N * 128 * 2) : nullptr;

    bf16* wb_pre1 = wb;
    bf16* wb_pre2 = wb_pre1 + 32768;
    bf16* wb_c1   = wb_pre2 + 32768;
    bf16* wb_c2   = wb_c1 + 16384;
    bf16* wb_g1i  = wb_c2 + 16384;
    bf16* wb_g1h  = wb_g1i + 49152;
    bf16* wb_g2i  = wb_g1h + 49152;
    bf16* wb_g2h  = wb_g2i + 49152;

    const int gB = 256;
    const dim3 blk(gB);
    const int grid_rows128 = (N + 127) / 128;
    const int grid_gru     = (N + 63) / 64;
    const int grid_E       = (E + gB - 1) / gB;

    cvt8_kernel<<<(294912 + 255) / 256, blk, 0, stream>>>(
        w_pre1, w_pre2, w_c1, w_c2, g1_wih, g1_whh, g2_wih, g2_whh, wb);

    // ---- CSR build + hierarchical degree-sort perm ----
    hipMemsetAsync(degi, 0, (size_t)N * 4, stream);
    deg_kernel<<<grid_E, blk, 0, stream>>>(ei + E, degi, E);
    scan1_kernel<<<nbB, blk, 0, stream>>>(degi, inc, bsum, dinv, N);
    scan2_kernel<<<1, 512, 0, stream>>>(bsum, nbB);
    scan3_kernel<<<nbB, blk, 0, stream>>>(inc, degi, bsum, rowptr, rp2, N);
    fill_kernel<<<grid_E, blk, 0, stream>>>(ei, ei + E, rp2, dinv, csr_pk, E);
    bhist_kernel<<<nbB, blk, 0, stream>>>(degi, binof, rankin, bh, N, nbB);
    gscan_kernel<<<1, blk, 0, stream>>>(bh, 64 * nbB);
    pscatter_kernel<<<nbB, blk, 0, stream>>>(binof, rankin, bh, perm, N, nbB);

    // ---- preprocess: x -> H1b (bf16) -> H2b (bf16) ----
    gemm_kernel<128, 256, true, true, float, bf16><<<grid_rows128, blk, 0, stream>>>(x, wb_pre1, b_pre1, H1b, N);
    gemm_kernel<256, 128, true, true, bf16,  bf16><<<grid_rows128, blk, 0, stream>>>(H1b, wb_pre2, b_pre2, H2b, N);

    // GRU1: emb0 = gru(H2b, prev0)
    gru_kernel<bf16><<<grid_gru, blk, 0, stream>>>(H2b, prev0, wb_g1i, wb_g1h, g1_bih, g1_bhh, emb0, N);

    auto run_gemm = [&](const float* hin, const bf16* wp) {
        switch (cw) {
        case 128: gemm_kernel<128, 128, false, false, float, bf16><<<grid_rows128, blk, 0, stream>>>(hin, wp, nullptr, xwb, N); break;
        case 64:  gemm_kernel<128, 64,  false, false, float, bf16><<<grid_rows128, blk, 0, stream>>>(hin, wp, nullptr, xwb, N); break;
        case 32:  gemm_kernel<128, 32,  false, false, float, bf16><<<grid_rows128, blk, 0, stream>>>(hin, wp, nullptr, xwb, N); break;
        default:  gemm_kernel<128, 16,  false, false, float, bf16><<<grid_rows128, blk, 0, stream>>>(hin, wp, nullptr, xwb, N); break;
        }
    };

    if (fused) {
        // conv1 + GRU2 fused: emb0 -> xwb -> (gather+gru, degree-sorted) -> emb1
        run_gemm(emb0, wb_c1);
        gg_kernel<<<grid_gru, blk, 0, stream>>>(xwb, rowptr, degi, csr_pk, perm,
                                                dinv, b_c1, prev0,
                                                wb_g1i, wb_g1h, g1_bih, g1_bhh, emb1, N);
        // conv2 + GRU3 fused: emb1 -> xwb -> (gather+gru, degree-sorted) -> emb2
        run_gemm(emb1, wb_c2);
        gg_kernel<<<grid_gru, blk, 0, stream>>>(xwb, rowptr, degi, csr_pk, perm,
                                                dinv, b_c2, prev1,
                                                wb_g2i, wb_g2h, g2_bih, g2_bhh, emb2, N);
    } else {
        const int grid_ga = (int)((((long)N << lg) + gB - 1) / gB);
        for (int ps = 0; ps < passes; ++ps) {
            run_gemm(emb0, wb_c1 + (size_t)(ps * cw) * 128);
            gather_kernel<bf16><<<grid_ga, blk, 0, stream>>>(xwb, rowptr, degi, csr_pk,
                                                             dinv, b_c1, h1b, N, ps * cw, cw, lg);
        }
        gru_kernel<bf16><<<grid_gru, blk, 0, stream>>>(h1b, prev0, wb_g1i, wb_g1h, g1_bih, g1_bhh, emb1, N);
        for (int ps = 0; ps < passes; ++ps) {
            run_gemm(emb1, wb_c2 + (size_t)(ps * cw) * 128);
            if (big_ws)
                gather_kernel<bf16><<<grid_ga, blk, 0, stream>>>(xwb, rowptr, degi, csr_pk,
                                                                 dinv, b_c2, h2b, N, ps * cw, cw, lg);
            else
                gather_kernel<float><<<grid_ga, blk, 0, stream>>>(xwb, rowptr, degi, csr_pk,
                                                                  dinv, b_c2, emb2, N, ps * cw, cw, lg);
        }
        if (big_ws)
            gru_kernel<bf16><<<grid_gru, blk, 0, stream>>>(h2b, prev1, wb_g2i, wb_g2h, g2_bih, g2_bhh, emb2, N);
        else
            gru_kernel<float><<<grid_gru, blk, 0, stream>>>(emb2, prev1, wb_g2i, wb_g2h, g2_bih, g2_bhh, emb2, N);
    }

    // LP head (16 lanes/edge)
    lp_kernel<<<(int)(((long)EL * 16 + gB - 1) / gB), blk, 0, stream>>>(emb2, eli, w_post, b_post, logits, EL);
}

// Round 17
// 525.264 us; speedup vs baseline: 1.0940x; 1.0940x over previous
//
#include <hip/hip_runtime.h>
#include <hip/hip_bf16.h>
#include <type_traits>

// ---------------------------------------------------------------------------
// ROLAND GNN forward. Buffers f32; matmuls bf16-MFMA, f32 accum.
// Outputs (concat, f32): logits[EL], emb0[N,128], emb1[N,128], emb2[N,128]
// Round 17: revert to round-15 (best: 531us). r16's degree-sort perm was
// neutral on gg (+worse L2 locality) and its build cost +40us -> gather is
// per-edge-latency-bound, not straggler-bound. Final structure:
//   cvt8 | CSR chain (6 kernels) | pre-GEMMs (bf16 intermediates in dead
//   output slots) | GRU1 | [GEMM -> fused gather+GRU] x2 | 16-lane LP head.
// ---------------------------------------------------------------------------

typedef __bf16 bf16;
typedef __bf16 bf16x8 __attribute__((ext_vector_type(8)));
typedef float  f32x4  __attribute__((ext_vector_type(4)));

#define DEV __device__ __forceinline__

DEV f32x4 mfma16(bf16x8 a, bf16x8 b, f32x4 c) {
    return __builtin_amdgcn_mfma_f32_16x16x32_bf16(a, b, c, 0, 0, 0);
}

DEV bf16x8 load_a8(const float* p) {
    f32x4 lo = *(const f32x4*)p;
    f32x4 hi = *(const f32x4*)(p + 4);
    bf16x8 v;
    v[0] = (bf16)lo[0]; v[1] = (bf16)lo[1]; v[2] = (bf16)lo[2]; v[3] = (bf16)lo[3];
    v[4] = (bf16)hi[0]; v[5] = (bf16)hi[1]; v[6] = (bf16)hi[2]; v[7] = (bf16)hi[3];
    return v;
}
DEV bf16x8 load_a8(const bf16* p) { return *(const bf16x8*)p; }

// single fused f32->bf16 conversion of all 8 weight matrices into wb
__global__ void cvt8_kernel(const float* s0, const float* s1, const float* s2, const float* s3,
                            const float* s4, const float* s5, const float* s6, const float* s7,
                            bf16* __restrict__ wb) {
    const int i = blockIdx.x * 256 + threadIdx.x;
    if (i >= 294912) return;
    float v;
    if      (i < 32768)  v = s0[i];
    else if (i < 65536)  v = s1[i - 32768];
    else if (i < 81920)  v = s2[i - 65536];
    else if (i < 98304)  v = s3[i - 81920];
    else if (i < 147456) v = s4[i - 98304];
    else if (i < 196608) v = s5[i - 147456];
    else if (i < 245760) v = s6[i - 196608];
    else                 v = s7[i - 245760];
    wb[i] = (bf16)v;
}

// ---------------------------------------------------------------------------
// GEMM: C[M,Co] = act(A[M,Ci] @ W[Co,Ci]^T + bias). 2 M-tiles/wave.
// MFMA 16x16x32 bf16; C/D layout (m89): col=lane&15, row=4*(lane>>4)+j.
// ---------------------------------------------------------------------------
template<int Ci, int Co, bool ACT, bool BIAS, typename AT, typename OT>
__global__ __launch_bounds__(256) void gemm_kernel(
    const AT* __restrict__ A, const bf16* __restrict__ W,
    const float* __restrict__ bias, OT* __restrict__ C, int M)
{
    const int tid  = threadIdx.x;
    const int lane = tid & 63, w = tid >> 6;
    const int lr   = lane & 15, ko = lane >> 4;
    const int rbase = blockIdx.x * 128 + w * 32;

    constexpr int KC = Ci / 32;
    constexpr int NT = Co / 16;

    bf16x8 a[2][KC];
#pragma unroll
    for (int m = 0; m < 2; ++m) {
        long arow = rbase + m * 16 + lr; if (arow > M - 1) arow = M - 1;  // clamped rows never stored
#pragma unroll
        for (int kc = 0; kc < KC; ++kc)
            a[m][kc] = load_a8(A + arow * Ci + kc * 32 + ko * 8);
    }

#pragma unroll
    for (int t = 0; t < NT; ++t) {
        f32x4 acc0 = {0.f, 0.f, 0.f, 0.f};
        f32x4 acc1 = {0.f, 0.f, 0.f, 0.f};
        const bf16* wp = W + (long)(t * 16 + lr) * Ci + ko * 8;
#pragma unroll
        for (int kc = 0; kc < KC; ++kc) {
            bf16x8 wf = *(const bf16x8*)(wp + kc * 32);
            acc0 = mfma16(a[0][kc], wf, acc0);
            acc1 = mfma16(a[1][kc], wf, acc1);
        }

        const int col = t * 16 + lr;
        float bv = 0.f;
        if (BIAS) bv = bias[col];
#pragma unroll
        for (int j = 0; j < 4; ++j) {
            const int r0 = rbase + ko * 4 + j;
            if (r0 < M) {
                float v = acc0[j] + bv;
                if (ACT) v = (v >= 0.f) ? v : 0.01f * v;
                C[(long)r0 * Co + col] = (OT)v;
            }
            const int r1 = rbase + 16 + ko * 4 + j;
            if (r1 < M) {
                float v = acc1[j] + bv;
                if (ACT) v = (v >= 0.f) ? v : 0.01f * v;
                C[(long)r1 * Co + col] = (OT)v;
            }
        }
    }
}

// ---------------------------------------------------------------------------
// GRUCell, 64-row blocks (4 waves x 16 rows), LDS weight tiles + reg prefetch.
// Safe for out == x (f32 path): all A-frag reads precede the first barrier.
// ---------------------------------------------------------------------------
template<typename XT>
__global__ __launch_bounds__(256) void gru_kernel(
    const XT* x, const float* __restrict__ hp,
    const bf16* __restrict__ wih, const bf16* __restrict__ whh,
    const float* __restrict__ bih, const float* __restrict__ bhh,
    float* out, int N)
{
    __shared__ bf16 Lw[6][16][128];   // 24 KB

    const int tid  = threadIdx.x;
    const int lane = tid & 63, w = tid >> 6;
    const int lr   = lane & 15, ko = lane >> 4;
    const long rbase = (long)blockIdx.x * 64 + w * 16;

    long arow = rbase + lr; if (arow > N - 1) arow = N - 1;
    bf16x8 ax[4], ah[4];
#pragma unroll
    for (int kc = 0; kc < 4; ++kc) {
        ax[kc] = load_a8(x  + arow * 128 + kc * 32 + ko * 8);
        ah[kc] = load_a8(hp + arow * 128 + kc * 32 + ko * 8);
    }

    bf16x8 pre[6];
    auto LDW = [&](int tc) {
#pragma unroll
        for (int i = 0; i < 6; ++i) {
            const int ch  = tid + 256 * i;
            const int g   = ch >> 8, rem = ch & 255;
            const int row = rem >> 4, cc = rem & 15;
            const int scc = cc ^ (row & 7);
            pre[i] = *(const bf16x8*)((g < 3 ? wih : whh)
                + (long)(((g % 3) * 128 + tc * 16 + row) * 128 + scc * 8));
        }
    };
    LDW(0);

    for (int tc = 0; tc < 8; ++tc) {
        __syncthreads();
#pragma unroll
        for (int i = 0; i < 6; ++i) {
            const int ch  = tid + 256 * i;
            const int g   = ch >> 8, rem = ch & 255;
            const int row = rem >> 4, cc = rem & 15;
            *(bf16x8*)(&Lw[g][row][cc * 8]) = pre[i];
        }
        __syncthreads();
        if (tc < 7) LDW(tc + 1);

        const int col = tc * 16 + lr;
        const float br = bih[col]       + bhh[col];
        const float bz = bih[128 + col] + bhh[128 + col];
        const float bi = bih[256 + col];
        const float bh = bhh[256 + col];

        f32x4 ar = {0.f, 0.f, 0.f, 0.f};
        f32x4 az = {0.f, 0.f, 0.f, 0.f};
        f32x4 ai = {0.f, 0.f, 0.f, 0.f};
        f32x4 ag = {0.f, 0.f, 0.f, 0.f};
#pragma unroll
        for (int kc = 0; kc < 4; ++kc) {
            const int cc = (kc * 4 + ko) ^ (lr & 7);
            bf16x8 wr_i = *(const bf16x8*)(&Lw[0][lr][cc * 8]);
            bf16x8 wz_i = *(const bf16x8*)(&Lw[1][lr][cc * 8]);
            bf16x8 wn_i = *(const bf16x8*)(&Lw[2][lr][cc * 8]);
            bf16x8 wr_h = *(const bf16x8*)(&Lw[3][lr][cc * 8]);
            bf16x8 wz_h = *(const bf16x8*)(&Lw[4][lr][cc * 8]);
            bf16x8 wn_h = *(const bf16x8*)(&Lw[5][lr][cc * 8]);
            ar = mfma16(ax[kc], wr_i, ar);
            ar = mfma16(ah[kc], wr_h, ar);
            az = mfma16(ax[kc], wz_i, az);
            az = mfma16(ah[kc], wz_h, az);
            ai = mfma16(ax[kc], wn_i, ai);
            ag = mfma16(ah[kc], wn_h, ag);
        }
#pragma unroll
        for (int j = 0; j < 4; ++j) {
            const long row = rbase + ko * 4 + j;
            if (row < N) {
                const float r = 1.f / (1.f + __expf(-(ar[j] + br)));
                const float z = 1.f / (1.f + __expf(-(az[j] + bz)));
                const float pre_ = (ai[j] + bi) + r * (ag[j] + bh);
                const float n = 1.f - 2.f / (1.f + __expf(2.f * pre_));
                out[row * 128 + col] = (1.f - z) * n + z * hp[row * 128 + col];
            }
        }
    }
}

// ---------------------------------------------------------------------------
// FUSED gather + GRU: conv output h computed per-lane directly in the MFMA
// A-fragment layout. Gather uses packed int2 edge records (one 8B load per
// edge) and 2-edge unrolling (8 independent row-loads in flight).
// ---------------------------------------------------------------------------
__global__ __launch_bounds__(256) void gg_kernel(
    const bf16* __restrict__ xwb,
    const int* __restrict__ rowptr, const int* __restrict__ degi,
    const int2* __restrict__ csr_pk,
    const float* __restrict__ dinv, const float* __restrict__ cbias,
    const float* __restrict__ hp,
    const bf16* __restrict__ wih, const bf16* __restrict__ whh,
    const float* __restrict__ bih, const float* __restrict__ bhh,
    float* __restrict__ out, int N)
{
    __shared__ bf16 Lw[6][16][128];   // 24 KB

    const int tid  = threadIdx.x;
    const int lane = tid & 63, w = tid >> 6;
    const int lr   = lane & 15, ko = lane >> 4;
    const long rbase = (long)blockIdx.x * 64 + w * 16;

    long arow = rbase + lr; if (arow > N - 1) arow = N - 1;

    // ---- gather phase: 2-edge unrolled, packed records ----
    float acc[4][8];
#pragma unroll
    for (int kc = 0; kc < 4; ++kc)
#pragma unroll
        for (int j = 0; j < 8; ++j) acc[kc][j] = 0.f;
    {
        const int start = rowptr[arow];
        const int deg   = degi[arow];
        const bf16* xb  = xwb + ko * 8;
        int k = 0;
        for (; k + 2 <= deg; k += 2) {
            const int2 p0 = csr_pk[start + k];
            const int2 p1 = csr_pk[start + k + 1];
            const float nm0 = __int_as_float(p0.y);
            const float nm1 = __int_as_float(p1.y);
            const bf16* vp0 = xb + (long)p0.x * 128;
            const bf16* vp1 = xb + (long)p1.x * 128;
            bf16x8 a0 = *(const bf16x8*)(vp0);
            bf16x8 a1 = *(const bf16x8*)(vp0 + 32);
            bf16x8 a2 = *(const bf16x8*)(vp0 + 64);
            bf16x8 a3 = *(const bf16x8*)(vp0 + 96);
            bf16x8 b0 = *(const bf16x8*)(vp1);
            bf16x8 b1 = *(const bf16x8*)(vp1 + 32);
            bf16x8 b2 = *(const bf16x8*)(vp1 + 64);
            bf16x8 b3 = *(const bf16x8*)(vp1 + 96);
#pragma unroll
            for (int j = 0; j < 8; ++j) {
                acc[0][j] += (float)a0[j] * nm0 + (float)b0[j] * nm1;
                acc[1][j] += (float)a1[j] * nm0 + (float)b1[j] * nm1;
                acc[2][j] += (float)a2[j] * nm0 + (float)b2[j] * nm1;
                acc[3][j] += (float)a3[j] * nm0 + (float)b3[j] * nm1;
            }
        }
        if (k < deg) {
            const int2 p0 = csr_pk[start + k];
            const float nm0 = __int_as_float(p0.y);
            const bf16* vp0 = xb + (long)p0.x * 128;
            bf16x8 a0 = *(const bf16x8*)(vp0);
            bf16x8 a1 = *(const bf16x8*)(vp0 + 32);
            bf16x8 a2 = *(const bf16x8*)(vp0 + 64);
            bf16x8 a3 = *(const bf16x8*)(vp0 + 96);
#pragma unroll
            for (int j = 0; j < 8; ++j) {
                acc[0][j] += (float)a0[j] * nm0;
                acc[1][j] += (float)a1[j] * nm0;
                acc[2][j] += (float)a2[j] * nm0;
                acc[3][j] += (float)a3[j] * nm0;
            }
        }
    }

    bf16x8 ax[4], ah[4];
    {
        const float di = dinv[arow], sl = di * di;
        const bf16* vp = xwb + (long)arow * 128 + ko * 8;
#pragma unroll
        for (int kc = 0; kc < 4; ++kc) {
            bf16x8 vd = *(const bf16x8*)(vp + kc * 32);
#pragma unroll
            for (int j = 0; j < 8; ++j) {
                float t = acc[kc][j] + (float)vd[j] * sl + cbias[kc * 32 + ko * 8 + j];
                t = (t >= 0.f) ? t : 0.01f * t;
                ax[kc][j] = (bf16)t;
            }
            ah[kc] = load_a8(hp + arow * 128 + kc * 32 + ko * 8);
        }
    }

    // ---- GRU phase ----
    bf16x8 pre[6];
    auto LDW = [&](int tc) {
#pragma unroll
        for (int i = 0; i < 6; ++i) {
            const int ch  = tid + 256 * i;
            const int g   = ch >> 8, rem = ch & 255;
            const int row = rem >> 4, cc = rem & 15;
            const int scc = cc ^ (row & 7);
            pre[i] = *(const bf16x8*)((g < 3 ? wih : whh)
                + (long)(((g % 3) * 128 + tc * 16 + row) * 128 + scc * 8));
        }
    };
    LDW(0);

    for (int tc = 0; tc < 8; ++tc) {
        __syncthreads();
#pragma unroll
        for (int i = 0; i < 6; ++i) {
            const int ch  = tid + 256 * i;
            const int g   = ch >> 8, rem = ch & 255;
            const int row = rem >> 4, cc = rem & 15;
            *(bf16x8*)(&Lw[g][row][cc * 8]) = pre[i];
        }
        __syncthreads();
        if (tc < 7) LDW(tc + 1);

        const int col = tc * 16 + lr;
        const float br = bih[col]       + bhh[col];
        const float bz = bih[128 + col] + bhh[128 + col];
        const float bi = bih[256 + col];
        const float bh = bhh[256 + col];

        f32x4 ar = {0.f, 0.f, 0.f, 0.f};
        f32x4 az = {0.f, 0.f, 0.f, 0.f};
        f32x4 ai = {0.f, 0.f, 0.f, 0.f};
        f32x4 ag = {0.f, 0.f, 0.f, 0.f};
        __builtin_amdgcn_s_setprio(1);
#pragma unroll
        for (int kc = 0; kc < 4; ++kc) {
            const int cc = (kc * 4 + ko) ^ (lr & 7);
            bf16x8 wr_i = *(const bf16x8*)(&Lw[0][lr][cc * 8]);
            bf16x8 wz_i = *(const bf16x8*)(&Lw[1][lr][cc * 8]);
            bf16x8 wn_i = *(const bf16x8*)(&Lw[2][lr][cc * 8]);
            bf16x8 wr_h = *(const bf16x8*)(&Lw[3][lr][cc * 8]);
            bf16x8 wz_h = *(const bf16x8*)(&Lw[4][lr][cc * 8]);
            bf16x8 wn_h = *(const bf16x8*)(&Lw[5][lr][cc * 8]);
            ar = mfma16(ax[kc], wr_i, ar);
            ar = mfma16(ah[kc], wr_h, ar);
            az = mfma16(ax[kc], wz_i, az);
            az = mfma16(ah[kc], wz_h, az);
            ai = mfma16(ax[kc], wn_i, ai);
            ag = mfma16(ah[kc], wn_h, ag);
        }
        __builtin_amdgcn_s_setprio(0);
#pragma unroll
        for (int j = 0; j < 4; ++j) {
            const long row = rbase + ko * 4 + j;
            if (row < N) {
                const float r = 1.f / (1.f + __expf(-(ar[j] + br)));
                const float z = 1.f / (1.f + __expf(-(az[j] + bz)));
                const float pre_ = (ai[j] + bi) + r * (ag[j] + bh);
                const float n = 1.f - 2.f / (1.f + __expf(2.f * pre_));
                out[row * 128 + col] = (1.f - z) * n + z * hp[row * 128 + col];
            }
        }
    }
}

// ---------------------------------------------------------------------------
// CSR build chain (kernel-boundary sync; NO grid.sync; NO concentrated atomics)
// ---------------------------------------------------------------------------
__global__ void deg_kernel(const int* __restrict__ dst, int* degi, int E) {
    const int e = blockIdx.x * 256 + threadIdx.x;
    if (e < E) atomicAdd(&degi[dst[e]], 1);
}
__global__ void scan1_kernel(const int* __restrict__ degi, int* __restrict__ inc,
                             int* __restrict__ bsum, float* __restrict__ dinv, int N) {
    __shared__ int s[256];
    const int i = blockIdx.x * 256 + threadIdx.x;
    const int d = (i < N) ? degi[i] : 0;
    if (i < N) dinv[i] = rsqrtf((float)d + 1.0f);   // +1 self loop
    s[threadIdx.x] = d;
    __syncthreads();
#pragma unroll
    for (int off = 1; off < 256; off <<= 1) {
        int t = (threadIdx.x >= off) ? s[threadIdx.x - off] : 0;
        __syncthreads();
        s[threadIdx.x] += t;
        __syncthreads();
    }
    if (i < N) inc[i] = s[threadIdx.x];
    if (threadIdx.x == 255) bsum[blockIdx.x] = s[255];
}
__global__ void scan2_kernel(int* bsum, int nb) {
    __shared__ int s[512];
    __shared__ int carry;
    if (threadIdx.x == 0) carry = 0;
    __syncthreads();
    for (int base = 0; base < nb; base += 512) {
        const int i = base + threadIdx.x;
        s[threadIdx.x] = (i < nb) ? bsum[i] : 0;
        __syncthreads();
#pragma unroll
        for (int off = 1; off < 512; off <<= 1) {
            int t = (threadIdx.x >= off) ? s[threadIdx.x - off] : 0;
            __syncthreads();
            s[threadIdx.x] += t;
            __syncthreads();
        }
        const int c = carry;
        if (i < nb) bsum[i] = s[threadIdx.x] + c;
        __syncthreads();
        if (threadIdx.x == 511) carry = c + s[511];
        __syncthreads();
    }
}
__global__ void scan3_kernel(const int* __restrict__ inc, const int* __restrict__ degi,
                             const int* __restrict__ bsum, int* __restrict__ rowptr,
                             int* __restrict__ rp2, int N) {
    const int i = blockIdx.x * 256 + threadIdx.x;
    if (i >= N) return;
    const int prev = (blockIdx.x > 0) ? bsum[blockIdx.x - 1] : 0;
    const int rp = prev + inc[i] - degi[i];   // exclusive prefix
    rowptr[i] = rp;
    rp2[i]    = rp;
}
__global__ void fill_kernel(const int* __restrict__ src, const int* __restrict__ dst,
                            int* rp2, const float* __restrict__ dinv,
                            int* __restrict__ csr_src, float* __restrict__ csr_norm,
                            int2* __restrict__ csr_pk, int E) {
    const int e = blockIdx.x * 256 + threadIdx.x;
    if (e >= E) return;
    const int s = src[e], d = dst[e];
    const int pos = atomicAdd(&rp2[d], 1);
    const float nm = dinv[s] * dinv[d];
    csr_src[pos]  = s;
    csr_norm[pos] = nm;
    csr_pk[pos]   = make_int2(s, __float_as_int(nm));
}

// ---------------------------------------------------------------------------
// Standalone gather (fallback path for small ws / column passes)
// ---------------------------------------------------------------------------
template<typename OT>
__global__ __launch_bounds__(256) void gather_kernel(
    const bf16* __restrict__ xwb,
    const int* __restrict__ rowptr, const int* __restrict__ degi,
    const int* __restrict__ csr_src, const float* __restrict__ csr_norm,
    const float* __restrict__ dinv, const float* __restrict__ bias,
    OT* __restrict__ out, int N, int colbase, int cw, int lg)
{
    const long tid = (long)blockIdx.x * 256 + threadIdx.x;
    const long d = tid >> lg;
    const int  c = (int)(tid & ((1 << lg) - 1));
    if (d >= N) return;

    const int start = rowptr[d];
    const int deg   = degi[d];
    const int h     = deg >> 1;
    const bf16* xb  = xwb + c * 8;

    float acca[8] = {0.f, 0.f, 0.f, 0.f, 0.f, 0.f, 0.f, 0.f};
    float accb[8] = {0.f, 0.f, 0.f, 0.f, 0.f, 0.f, 0.f, 0.f};
    for (int k = 0; k < h; ++k) {
        const int   sa = csr_src[start + k];
        const int   sb = csr_src[start + h + k];
        const float na = csr_norm[start + k];
        const float nb_ = csr_norm[start + h + k];
        bf16x8 va = *(const bf16x8*)(xb + (long)sa * cw);
        bf16x8 vb = *(const bf16x8*)(xb + (long)sb * cw);
#pragma unroll
        for (int j = 0; j < 8; ++j) {
            acca[j] += (float)va[j] * na;
            accb[j] += (float)vb[j] * nb_;
        }
    }
    if (deg & 1) {
        const int   s  = csr_src[start + deg - 1];
        const float nm = csr_norm[start + deg - 1];
        bf16x8 v = *(const bf16x8*)(xb + (long)s * cw);
#pragma unroll
        for (int j = 0; j < 8; ++j) acca[j] += (float)v[j] * nm;
    }

    const float di = dinv[d], sl = di * di;
    bf16x8 vd = *(const bf16x8*)(xb + d * cw);
    const int col = colbase + c * 8;
    float v[8];
#pragma unroll
    for (int j = 0; j < 8; ++j) {
        float t = acca[j] + accb[j] + (float)vd[j] * sl + bias[col + j];
        v[j] = (t >= 0.f) ? t : 0.01f * t;
    }
    if constexpr (std::is_same<OT, bf16>::value) {
        bf16x8 o;
#pragma unroll
        for (int j = 0; j < 8; ++j) o[j] = (bf16)v[j];
        *(bf16x8*)(out + d * 128 + col) = o;
    } else {
        f32x4 o0, o1;
#pragma unroll
        for (int j = 0; j < 4; ++j) { o0[j] = v[j]; o1[j] = v[4 + j]; }
        *(f32x4*)(out + d * 128 + col)     = o0;
        *(f32x4*)(out + d * 128 + col + 4) = o1;
    }
}

// ---------------------------------------------------------------------------
// LP head: 16 lanes per edge, shfl reduce.
// ---------------------------------------------------------------------------
__global__ __launch_bounds__(256) void lp_kernel(
    const float* __restrict__ emb, const int* __restrict__ eli,
    const float* __restrict__ wpost, const float* __restrict__ bpost,
    float* __restrict__ logits, int EL)
{
    const long t = (long)blockIdx.x * 256 + threadIdx.x;
    const long e = t >> 4;
    const int  c = (int)(t & 15);
    if (e >= EL) return;
    const long s = eli[e], d = eli[EL + e];

    f32x4 a0 = *(const f32x4*)(emb + s * 128 + c * 8);
    f32x4 a1 = *(const f32x4*)(emb + s * 128 + c * 8 + 4);
    f32x4 b0 = *(const f32x4*)(emb + d * 128 + c * 8);
    f32x4 b1 = *(const f32x4*)(emb + d * 128 + c * 8 + 4);
    f32x4 w00 = *(const f32x4*)(wpost + c * 8);
    f32x4 w01 = *(const f32x4*)(wpost + c * 8 + 4);
    f32x4 w10 = *(const f32x4*)(wpost + 128 + c * 8);
    f32x4 w11 = *(const f32x4*)(wpost + 128 + c * 8 + 4);

    float acc = 0.f;
#pragma unroll
    for (int i = 0; i < 4; ++i) {
        acc += a0[i] * b0[i] * (w00[i] + w10[i]);
        acc += a1[i] * b1[i] * (w01[i] + w11[i]);
    }
#pragma unroll
    for (int m = 1; m < 16; m <<= 1) acc += __shfl_xor(acc, m);
    if (c == 0) logits[e] = acc + bpost[0] + bpost[1];
}

// ---------------------------------------------------------------------------
extern "C" void kernel_launch(void* const* d_in, const int* in_sizes, int n_in,
                              void* d_out, int out_size, void* d_ws, size_t ws_size,
                              hipStream_t stream) {
    const float* x      = (const float*)d_in[0];
    const int*   ei     = (const int*)d_in[1];   // [2,E]: row0=src, row1=dst
    const int*   eli    = (const int*)d_in[2];
    const float* prev0  = (const float*)d_in[3];
    const float* prev1  = (const float*)d_in[4];
    const float* w_pre1 = (const float*)d_in[5];
    const float* b_pre1 = (const float*)d_in[6];
    const float* w_pre2 = (const float*)d_in[7];
    const float* b_pre2 = (const float*)d_in[8];
    const float* w_c1   = (const float*)d_in[9];
    const float* b_c1   = (const float*)d_in[10];
    const float* w_c2   = (const float*)d_in[11];
    const float* b_c2   = (const float*)d_in[12];
    const float* w_post = (const float*)d_in[13];
    const float* b_post = (const float*)d_in[14];
    const float* g1_wih = (const float*)d_in[15];
    const float* g1_whh = (const float*)d_in[16];
    const float* g1_bih = (const float*)d_in[17];
    const float* g1_bhh = (const float*)d_in[18];
    const float* g2_wih = (const float*)d_in[19];
    const float* g2_whh = (const float*)d_in[20];
    const float* g2_bih = (const float*)d_in[21];
    const float* g2_bhh = (const float*)d_in[22];

    const int N  = in_sizes[0] / 128;
    const int E  = in_sizes[1] / 2;
    const int EL = in_sizes[2] / 2;
    const long NH = (long)N * 128;

    // outputs (f32)
    float* out    = (float*)d_out;
    float* logits = out;
    float* emb0   = out + EL;
    float* emb1   = emb0 + NH;
    float* emb2   = emb1 + NH;

    // bf16 intermediates in currently-dead output slots
    bf16* H1b = (bf16*)emb1;   // [N,256] bf16 == emb1 slot
    bf16* H2b = (bf16*)emb2;   // [N,128] bf16 (first half of emb2 slot)
    bf16* h1b = (bf16*)emb2;   // fallback only

    // ---- workspace layout ----
    char* ws = (char*)d_ws;
    size_t p = 0;
    auto alloc = [&](size_t bytes) { size_t o = p; p = (p + bytes + 255) & ~(size_t)255; return o; };
    float* dinv    = (float*)(ws + alloc((size_t)N * 4));
    int*   degi    = (int*)  (ws + alloc((size_t)N * 4));
    int*   inc     = (int*)  (ws + alloc((size_t)N * 4));
    int*   rowptr  = (int*)  (ws + alloc((size_t)(N + 1) * 4));
    int*   rp2     = (int*)  (ws + alloc((size_t)N * 4));
    int*   bsum    = (int*)  (ws + alloc(4096));
    bf16*  wb      = (bf16*) (ws + alloc((size_t)294912 * 2));
    int*   csr_src = (int*)  (ws + alloc((size_t)E * 4));
    float* csr_nrm = (float*)(ws + alloc((size_t)E * 4));
    int2*  csr_pk  = (int2*) (ws + alloc((size_t)E * 8));
    const size_t fixed = p;
    bf16*  xwb     = (bf16*)(ws + fixed);

    int cw = 128;
    while (cw > 16 && fixed + (size_t)N * cw * 2 > ws_size) cw >>= 1;
    const int lg = __builtin_ctz(cw >> 3);
    const int passes = 128 / cw;
    const bool fused = (cw == 128);
    const bool big_ws = fused &&
        (ws_size >= fixed + (size_t)N * 128 * 2 + (size_t)N * 128 * 2);
    bf16* h2b = big_ws ? (bf16*)(ws + fixed + (size_t)N * 128 * 2) : nullptr;

    bf16* wb_pre1 = wb;
    bf16* wb_pre2 = wb_pre1 + 32768;
    bf16* wb_c1   = wb_pre2 + 32768;
    bf16* wb_c2   = wb_c1 + 16384;
    bf16* wb_g1i  = wb_c2 + 16384;
    bf16* wb_g1h  = wb_g1i + 49152;
    bf16* wb_g2i  = wb_g1h + 49152;
    bf16* wb_g2h  = wb_g2i + 49152;

    const int gB = 256;
    const dim3 blk(gB);
    const int grid_rows128 = (N + 127) / 128;
    const int grid_gru     = (N + 63) / 64;
    const int grid_E       = (E + gB - 1) / gB;
    const int nb           = (N + 255) / 256;

    cvt8_kernel<<<(294912 + 255) / 256, blk, 0, stream>>>(
        w_pre1, w_pre2, w_c1, w_c2, g1_wih, g1_whh, g2_wih, g2_whh, wb);

    // ---- CSR build ----
    hipMemsetAsync(degi, 0, (size_t)N * 4, stream);
    deg_kernel<<<grid_E, blk, 0, stream>>>(ei + E, degi, E);
    scan1_kernel<<<nb, blk, 0, stream>>>(degi, inc, bsum, dinv, N);
    scan2_kernel<<<1, 512, 0, stream>>>(bsum, nb);
    scan3_kernel<<<nb, blk, 0, stream>>>(inc, degi, bsum, rowptr, rp2, N);
    fill_kernel<<<grid_E, blk, 0, stream>>>(ei, ei + E, rp2, dinv, csr_src, csr_nrm, csr_pk, E);

    // ---- preprocess: x -> H1b (bf16) -> H2b (bf16) ----
    gemm_kernel<128, 256, true, true, float, bf16><<<grid_rows128, blk, 0, stream>>>(x, wb_pre1, b_pre1, H1b, N);
    gemm_kernel<256, 128, true, true, bf16,  bf16><<<grid_rows128, blk, 0, stream>>>(H1b, wb_pre2, b_pre2, H2b, N);

    // GRU1: emb0 = gru(H2b, prev0)
    gru_kernel<bf16><<<grid_gru, blk, 0, stream>>>(H2b, prev0, wb_g1i, wb_g1h, g1_bih, g1_bhh, emb0, N);

    auto run_gemm = [&](const float* hin, const bf16* wp) {
        switch (cw) {
        case 128: gemm_kernel<128, 128, false, false, float, bf16><<<grid_rows128, blk, 0, stream>>>(hin, wp, nullptr, xwb, N); break;
        case 64:  gemm_kernel<128, 64,  false, false, float, bf16><<<grid_rows128, blk, 0, stream>>>(hin, wp, nullptr, xwb, N); break;
        case 32:  gemm_kernel<128, 32,  false, false, float, bf16><<<grid_rows128, blk, 0, stream>>>(hin, wp, nullptr, xwb, N); break;
        default:  gemm_kernel<128, 16,  false, false, float, bf16><<<grid_rows128, blk, 0, stream>>>(hin, wp, nullptr, xwb, N); break;
        }
    };

    if (fused) {
        // conv1 + GRU2 fused: emb0 -> xwb -> (gather+gru) -> emb1
        run_gemm(emb0, wb_c1);
        gg_kernel<<<grid_gru, blk, 0, stream>>>(xwb, rowptr, degi, csr_pk,
                                                dinv, b_c1, prev0,
                                                wb_g1i, wb_g1h, g1_bih, g1_bhh, emb1, N);
        // conv2 + GRU3 fused: emb1 -> xwb -> (gather+gru) -> emb2
        run_gemm(emb1, wb_c2);
        gg_kernel<<<grid_gru, blk, 0, stream>>>(xwb, rowptr, degi, csr_pk,
                                                dinv, b_c2, prev1,
                                                wb_g2i, wb_g2h, g2_bih, g2_bhh, emb2, N);
    } else {
        const int grid_ga = (int)((((long)N << lg) + gB - 1) / gB);
        for (int ps = 0; ps < passes; ++ps) {
            run_gemm(emb0, wb_c1 + (size_t)(ps * cw) * 128);
            gather_kernel<bf16><<<grid_ga, blk, 0, stream>>>(xwb, rowptr, degi, csr_src, csr_nrm,
                                                             dinv, b_c1, h1b, N, ps * cw, cw, lg);
        }
        gru_kernel<bf16><<<grid_gru, blk, 0, stream>>>(h1b, prev0, wb_g1i, wb_g1h, g1_bih, g1_bhh, emb1, N);
        for (int ps = 0; ps < passes; ++ps) {
            run_gemm(emb1, wb_c2 + (size_t)(ps * cw) * 128);
            if (big_ws)
                gather_kernel<bf16><<<grid_ga, blk, 0, stream>>>(xwb, rowptr, degi, csr_src, csr_nrm,
                                                                 dinv, b_c2, h2b, N, ps * cw, cw, lg);
            else
                gather_kernel<float><<<grid_ga, blk, 0, stream>>>(xwb, rowptr, degi, csr_src, csr_nrm,
                                                                  dinv, b_c2, emb2, N, ps * cw, cw, lg);
        }
        if (big_ws)
            gru_kernel<bf16><<<grid_gru, blk, 0, stream>>>(h2b, prev1, wb_g2i, wb_g2h, g2_bih, g2_bhh, emb2, N);
        else
            gru_kernel<float><<<grid_gru, blk, 0, stream>>>(emb2, prev1, wb_g2i, wb_g2h, g2_bih, g2_bhh, emb2, N);
    }

    // LP head (16 lanes/edge)
    lp_kernel<<<(int)(((long)EL * 16 + gB - 1) / gB), blk, 0, stream>>>(emb2, eli, w_post, b_post, logits, EL);
}